// Round 8
// baseline (489.670 us; speedup 1.0000x reference)
//
#include <hip/hip_runtime.h>
#include <cstdint>

// GRU recurrent autoencoder, MI355X persistent-MFMA implementation, round 8.
// B=2048, T=128, X=38, H=128, 3H=384. fp32 I/O, fp16 MFMA operands,
// fp32 accumulation + fp32 recurrent state (in registers).
//
// Round-8 vs round 7: all single-chain variants plateau at ~2780 cyc/step
// while busy work is ~500-800 -> ~70% dependency stall (ds_read -> MFMA
// chain -> trans chain -> ds_write -> barrier, lockstep across waves).
//  * TWO independent recurrent chains per WG (BT=8 = 2 chains x 4 rows,
//    grid 256 = 1 WG/CU). Chains share ALL weight registers (same gate
//    columns). Per step both chains issue back-to-back; their latency
//    chains overlap -> 4 independent streams per SIMD (2 waves x 2 chains).
//  * Chain layout: batch row b at M-row 4b -> valid C data = reg 0,
//    batch = quad. 3 trans/lane/chain (total 6, same as r7).
//  * x pipeline kept as fp16 across steps: cvt at rotate (vmcnt wait sits
//    there anyway, ~1 step after issue) -> lower register demand.
//  * HS=144 halfs (72 dw = 8 mod 32): 4-row A-frag ds_read_b128 2-way
//    (free), h-writes bank-conflict-free (8q+8wv+m' distinct mod 32).
//  * Raw LDS barrier (lgkmcnt only), register x prefetch, decoder algebra
//    (r/z combined dWhh+dWih*linW, n-gate W2, overlapped projection,
//    t=0 pre-step) all carried from r7 (verified, absmax 2e-3).

#define T_SEQ 128
#define X_DIM 38
#define H_DIM 128
#define B_TOT 2048
#define BT    8
#define RC    4     // batch rows per chain
#define NCH   2     // chains per workgroup
#define HS    144   // h row stride in halfs (72 dw = 8 mod 32)

typedef _Float16 half8 __attribute__((ext_vector_type(8)));
typedef float    f32x4 __attribute__((ext_vector_type(4)));

__device__ __forceinline__ float fast_sigmoid(float x) {
    return __builtin_amdgcn_rcpf(1.0f + __expf(-x));
}
__device__ __forceinline__ float fast_tanh(float x) {
    return 1.0f - 2.0f * __builtin_amdgcn_rcpf(1.0f + __expf(2.0f * x));
}

// LDS-only barrier: no vmcnt drain -> global ops pipeline across steps.
#define LDS_BARRIER() asm volatile("s_waitcnt lgkmcnt(0)\n\ts_barrier" ::: "memory")

__global__ __launch_bounds__(512, 2)
void rae_gru_kernel(const float* __restrict__ x,
                    const float* __restrict__ eWih, const float* __restrict__ eWhh,
                    const float* __restrict__ ebih, const float* __restrict__ ebhh,
                    const float* __restrict__ dWih, const float* __restrict__ dWhh,
                    const float* __restrict__ dbih, const float* __restrict__ dbhh,
                    const float* __restrict__ linW, const float* __restrict__ linb,
                    float* __restrict__ out)
{
    __shared__ _Float16 hb[NCH][2][RC * HS];     // 4608 B, per-chain h dbuf
    __shared__ _Float16 w2lds[H_DIM * H_DIM];    // 32 KB, weight-fold staging

    const int tid  = threadIdx.x;
    const int wv   = tid >> 6;        // 0..7
    const int ln   = tid & 63;
    const int quad = ln >> 4;         // A/B: k-group; C/D: row-group (=batch)
    const int mrow = ln & 15;         // A: m-row / B,C: col-in-tile
    const int b0   = blockIdx.x * BT;
    const int arow = mrow >> 2;       // within-chain batch row this A-lane reads
    const int j    = wv * 16 + mrow;  // this lane's gate column (8 waves x 16)
    const int jc0  = j, jc1 = H_DIM + j, jc2 = 2 * H_DIM + j;

    {   // zero h state (h0 = 0)
        uint32_t* hz = (uint32_t*)&hb[0][0][0];
        for (int i = tid; i < (NCH * 2 * RC * HS) / 2; i += 512) hz[i] = 0u;
    }
    __syncthreads();

    // ---- persistent weight fragments (shared by both chains) ----
    half8 wh[3][4];    // enc: eWhh | dec: r/z combined, n pure dWhh
    half8 wxe[3][2];   // encoder Wih (K padded 38->64); dead after encoder
    half8 wxn[4];      // decoder n-gate W2
    half8 wl[4];       // linear head
    float b_r, b_z, b_ngi, b_ngh;

    // ---- encoder weights ----
    #pragma unroll
    for (int p = 0; p < 3; ++p) {
        const int jp = p * H_DIM + j;
        const float* wr = eWhh + (size_t)jp * H_DIM;
        #pragma unroll
        for (int c = 0; c < 4; ++c) {
            const int kb = c * 32 + quad * 8;
            half8 v;
            #pragma unroll
            for (int e = 0; e < 8; ++e) v[e] = (_Float16)wr[kb + e];
            wh[p][c] = v;
        }
        const float* wir = eWih + (size_t)jp * X_DIM;
        #pragma unroll
        for (int c = 0; c < 2; ++c) {
            const int kb = c * 32 + quad * 8;
            half8 v;
            #pragma unroll
            for (int e = 0; e < 8; ++e) {
                const int k = kb + e;
                v[e] = (k < X_DIM) ? (_Float16)wir[k] : (_Float16)0.0f;
            }
            wxe[p][c] = v;
        }
    }
    b_r   = ebih[jc0] + ebhh[jc0];
    b_z   = ebih[jc1] + ebhh[jc1];
    b_ngi = ebih[jc2];
    b_ngh = ebhh[jc2];

    float hold[NCH] = {0.0f, 0.0f};   // h[4ch+quad][j] in fp32

    // per-chain x base pointer (row = b0 + 4ch + arow)
    const float* xbase[NCH];
    #pragma unroll
    for (int ch = 0; ch < NCH; ++ch)
        xbase[ch] = x + (size_t)(b0 + RC * ch + arow) * T_SEQ * X_DIM;

    // fp16 x operands for current step + fp32 prefetch for next step
    half8 xA0[NCH], xA1[NCH];
    float xnf[NCH][8];
    float xn1f[NCH][6];

    // ---- initial load+cvt for t=0 ----
    #pragma unroll
    for (int ch = 0; ch < NCH; ++ch) {
        const float* xr = xbase[ch];
        float t0[8], t1[6];
        #pragma unroll
        for (int u = 0; u < 4; ++u) {
            float2 w = *(const float2*)(xr + quad * 8 + 2 * u);
            t0[2 * u] = w.x; t0[2 * u + 1] = w.y;
        }
        #pragma unroll
        for (int e = 0; e < 6; ++e) t1[e] = 0.0f;
        if (quad == 0) {
            #pragma unroll
            for (int u = 0; u < 3; ++u) {
                float2 w = *(const float2*)(xr + 32 + 2 * u);
                t1[2 * u] = w.x; t1[2 * u + 1] = w.y;
            }
        }
        half8 a0;
        #pragma unroll
        for (int e = 0; e < 8; ++e) a0[e] = (_Float16)t0[e];
        half8 a1 = a0;                 // quads 1-3: hits all-zero weights
        if (quad == 0) {
            #pragma unroll
            for (int e = 0; e < 6; ++e) a1[e] = (_Float16)t1[e];
            a1[6] = (_Float16)0.0f; a1[7] = (_Float16)0.0f;
        }
        xA0[ch] = a0; xA1[ch] = a1;
    }

    // ================= encoder (raw LDS barrier per step) =================
    #pragma unroll 1
    for (int t = 0; t < T_SEQ; ++t) {
        const bool pf = (t + 1 < T_SEQ);
        if (pf) {   // prefetch x(t+1), both chains; stays in flight
            #pragma unroll
            for (int ch = 0; ch < NCH; ++ch) {
                const float* xr = xbase[ch] + (size_t)(t + 1) * X_DIM;
                #pragma unroll
                for (int u = 0; u < 4; ++u) {
                    float2 w = *(const float2*)(xr + quad * 8 + 2 * u);
                    xnf[ch][2 * u] = w.x; xnf[ch][2 * u + 1] = w.y;
                }
                if (quad == 0) {
                    #pragma unroll
                    for (int u = 0; u < 3; ++u) {
                        float2 w = *(const float2*)(xr + 32 + 2 * u);
                        xn1f[ch][2 * u] = w.x; xn1f[ch][2 * u + 1] = w.y;
                    }
                }
            }
        }

        #pragma unroll
        for (int ch = 0; ch < NCH; ++ch) {
            const _Float16* hrd = hb[ch][t & 1];
            _Float16*       hwr = hb[ch][(t & 1) ^ 1];

            half8 ha[4];
            #pragma unroll
            for (int c = 0; c < 4; ++c)
                ha[c] = *(const half8*)&hrd[arow * HS + c * 32 + quad * 8];

            f32x4 gir = { b_r, b_r, b_r, b_r };
            gir = __builtin_amdgcn_mfma_f32_16x16x32_f16(xA0[ch], wxe[0][0], gir, 0, 0, 0);
            gir = __builtin_amdgcn_mfma_f32_16x16x32_f16(xA1[ch], wxe[0][1], gir, 0, 0, 0);
            f32x4 giz = { b_z, b_z, b_z, b_z };
            giz = __builtin_amdgcn_mfma_f32_16x16x32_f16(xA0[ch], wxe[1][0], giz, 0, 0, 0);
            giz = __builtin_amdgcn_mfma_f32_16x16x32_f16(xA1[ch], wxe[1][1], giz, 0, 0, 0);
            f32x4 gin = { b_ngi, b_ngi, b_ngi, b_ngi };
            gin = __builtin_amdgcn_mfma_f32_16x16x32_f16(xA0[ch], wxe[2][0], gin, 0, 0, 0);
            gin = __builtin_amdgcn_mfma_f32_16x16x32_f16(xA1[ch], wxe[2][1], gin, 0, 0, 0);

            f32x4 ghr = { 0.0f, 0.0f, 0.0f, 0.0f };
            f32x4 ghz = { 0.0f, 0.0f, 0.0f, 0.0f };
            f32x4 ghn = { b_ngh, b_ngh, b_ngh, b_ngh };
            #pragma unroll
            for (int c = 0; c < 4; ++c) {
                ghr = __builtin_amdgcn_mfma_f32_16x16x32_f16(ha[c], wh[0][c], ghr, 0, 0, 0);
                ghz = __builtin_amdgcn_mfma_f32_16x16x32_f16(ha[c], wh[1][c], ghz, 0, 0, 0);
                ghn = __builtin_amdgcn_mfma_f32_16x16x32_f16(ha[c], wh[2][c], ghn, 0, 0, 0);
            }

            // epilogue: valid C data = reg 0, batch row = quad
            const float r = fast_sigmoid(gir[0] + ghr[0]);
            const float z = fast_sigmoid(giz[0] + ghz[0]);
            const float n = fast_tanh(gin[0] + r * ghn[0]);
            const float h = n + z * (hold[ch] - n);
            hold[ch] = h;
            hwr[quad * HS + j] = (_Float16)h;
        }

        if (pf) {   // rotate: cvt fp32 prefetch -> fp16 operands (vmcnt waits here)
            #pragma unroll
            for (int ch = 0; ch < NCH; ++ch) {
                half8 a0;
                #pragma unroll
                for (int e = 0; e < 8; ++e) a0[e] = (_Float16)xnf[ch][e];
                half8 a1 = a0;
                if (quad == 0) {
                    #pragma unroll
                    for (int e = 0; e < 6; ++e) a1[e] = (_Float16)xn1f[ch][e];
                    a1[6] = (_Float16)0.0f; a1[7] = (_Float16)0.0f;
                }
                xA0[ch] = a0; xA1[ch] = a1;
            }
        }

        LDS_BARRIER();
    }

    // ================= decoder weight prep =================
    // Step A: pure dWhh frags + biases.
    #pragma unroll
    for (int p = 0; p < 3; ++p) {
        const float* wr = dWhh + (size_t)(p * H_DIM + j) * H_DIM;
        #pragma unroll
        for (int c = 0; c < 4; ++c) {
            const int kb = c * 32 + quad * 8;
            half8 v;
            #pragma unroll
            for (int e = 0; e < 8; ++e) v[e] = (_Float16)wr[kb + e];
            wh[p][c] = v;
        }
    }
    const float c_r0 = dbih[jc0] + dbhh[jc0];
    const float c_z0 = dbih[jc1] + dbhh[jc1];
    const float c_n0 = dbih[jc2];
    b_ngh = dbhh[jc2];

    // Step B: t=0 pre-step (gi = bias only), both chains.
    // h_enc in hb[ch][0] (T_SEQ even); write d_1 into hb[ch][1].
    #pragma unroll
    for (int ch = 0; ch < NCH; ++ch) {
        const _Float16* hrd = hb[ch][0];
        _Float16*       hwr = hb[ch][1];
        half8 ha[4];
        #pragma unroll
        for (int c = 0; c < 4; ++c)
            ha[c] = *(const half8*)&hrd[arow * HS + c * 32 + quad * 8];
        f32x4 ar = { c_r0, c_r0, c_r0, c_r0 };
        f32x4 az = { c_z0, c_z0, c_z0, c_z0 };
        f32x4 aghn = { b_ngh, b_ngh, b_ngh, b_ngh };
        #pragma unroll
        for (int c = 0; c < 4; ++c) {
            ar   = __builtin_amdgcn_mfma_f32_16x16x32_f16(ha[c], wh[0][c], ar, 0, 0, 0);
            az   = __builtin_amdgcn_mfma_f32_16x16x32_f16(ha[c], wh[1][c], az, 0, 0, 0);
            aghn = __builtin_amdgcn_mfma_f32_16x16x32_f16(ha[c], wh[2][c], aghn, 0, 0, 0);
        }
        const float r = fast_sigmoid(ar[0]);
        const float z = fast_sigmoid(az[0]);
        const float n = fast_tanh(c_n0 + r * aghn[0]);
        const float h = n + z * (hold[ch] - n);
        hold[ch] = h;
        hwr[quad * HS + j] = (_Float16)h;
    }
    __syncthreads();

    // Step C: fold W2 = dWih*linW. r/z: wh <- fp16(dWhh + W2); n: wxn <- fp16(W2).
    {
        const int kk = ((wv & 1) << 6) | ln;      // 0..127, lane's W2 column
        const int jb = (wv >> 1) * 32;            // 4 wave-pairs x 32 rows = 128
        float lc[X_DIM];
        #pragma unroll
        for (int m = 0; m < X_DIM; ++m) lc[m] = linW[m * H_DIM + kk];

        // gate 0 (r): combined
        #pragma unroll 1
        for (int jj = 0; jj < 32; ++jj) {
            const int jr = __builtin_amdgcn_readfirstlane(jb + jj);
            const float* dwr = dWih + (size_t)jr * X_DIM;
            float sacc = dWhh[(size_t)jr * H_DIM + kk];
            #pragma unroll
            for (int m = 0; m < X_DIM; ++m) sacc += dwr[m] * lc[m];
            w2lds[jr * H_DIM + kk] = (_Float16)sacc;
        }
        __syncthreads();
        #pragma unroll
        for (int c = 0; c < 4; ++c)
            wh[0][c] = *(const half8*)&w2lds[j * H_DIM + c * 32 + quad * 8];
        __syncthreads();

        // gate 1 (z): combined
        #pragma unroll 1
        for (int jj = 0; jj < 32; ++jj) {
            const int jr = __builtin_amdgcn_readfirstlane(jb + jj);
            const float* dwr = dWih + (size_t)(H_DIM + jr) * X_DIM;
            float sacc = dWhh[(size_t)(H_DIM + jr) * H_DIM + kk];
            #pragma unroll
            for (int m = 0; m < X_DIM; ++m) sacc += dwr[m] * lc[m];
            w2lds[jr * H_DIM + kk] = (_Float16)sacc;
        }
        __syncthreads();
        #pragma unroll
        for (int c = 0; c < 4; ++c)
            wh[1][c] = *(const half8*)&w2lds[j * H_DIM + c * 32 + quad * 8];
        __syncthreads();

        // gate 2 (n): W2 only (wh[2] stays pure dWhh)
        #pragma unroll 1
        for (int jj = 0; jj < 32; ++jj) {
            const int jr = __builtin_amdgcn_readfirstlane(jb + jj);
            const float* dwr = dWih + (size_t)(2 * H_DIM + jr) * X_DIM;
            float sacc = 0.0f;
            #pragma unroll
            for (int m = 0; m < X_DIM; ++m) sacc += dwr[m] * lc[m];
            w2lds[jr * H_DIM + kk] = (_Float16)sacc;
        }
        __syncthreads();
        #pragma unroll
        for (int c = 0; c < 4; ++c)
            wxn[c] = *(const half8*)&w2lds[j * H_DIM + c * 32 + quad * 8];
        __syncthreads();
    }

    // Step D: linear head frags + folded biases for t>=1.
    const int nlin = wv * 16 + mrow;          // waves 0..2 cover cols 0..47
    const bool nv = (wv < 3) && (nlin < X_DIM);
    float lb = 0.0f;
    {
        const float* lr = linW + (size_t)(nv ? nlin : 0) * H_DIM;
        #pragma unroll
        for (int c = 0; c < 4; ++c) {
            const int kb = c * 32 + quad * 8;
            half8 v;
            #pragma unroll
            for (int e = 0; e < 8; ++e)
                v[e] = nv ? (_Float16)lr[kb + e] : (_Float16)0.0f;
            wl[c] = v;
        }
        if (nv) lb = linb[nlin];
    }
    {
        float bf[3];
        #pragma unroll
        for (int p = 0; p < 3; ++p) {
            const float* dwr = dWih + (size_t)(p * H_DIM + j) * X_DIM;
            float sacc = 0.0f;
            #pragma unroll
            for (int m = 0; m < X_DIM; ++m) sacc += linb[m] * dwr[m];
            bf[p] = sacc;
        }
        b_r   = c_r0 + bf[0];
        b_z   = c_z0 + bf[1];
        b_ngi = c_n0 + bf[2];
    }

    // ================= decoder (t=1..127, raw LDS barrier per step) ========
    #pragma unroll 1
    for (int t = 1; t < T_SEQ; ++t) {
        #pragma unroll
        for (int ch = 0; ch < NCH; ++ch) {
            const _Float16* hrd = hb[ch][t & 1];
            _Float16*       hwr = hb[ch][(t & 1) ^ 1];

            half8 ha[4];
            #pragma unroll
            for (int c = 0; c < 4; ++c)
                ha[c] = *(const half8*)&hrd[arow * HS + c * 32 + quad * 8];

            // overlapped output projection: o_{t-1} = d_t @ linW^T + lb
            if (wv < 3) {
                f32x4 al = { lb, lb, lb, lb };
                #pragma unroll
                for (int c = 0; c < 4; ++c)
                    al = __builtin_amdgcn_mfma_f32_16x16x32_f16(ha[c], wl[c], al, 0, 0, 0);
                if (nv)
                    out[((size_t)(b0 + RC * ch + quad) * T_SEQ + (t - 1)) * X_DIM + nlin] = al[0];
            }

            f32x4 ar = { b_r, b_r, b_r, b_r };
            f32x4 az = { b_z, b_z, b_z, b_z };
            f32x4 aghn = { b_ngh, b_ngh, b_ngh, b_ngh };
            f32x4 agin = { b_ngi, b_ngi, b_ngi, b_ngi };
            #pragma unroll
            for (int c = 0; c < 4; ++c) {
                ar   = __builtin_amdgcn_mfma_f32_16x16x32_f16(ha[c], wh[0][c], ar, 0, 0, 0);
                az   = __builtin_amdgcn_mfma_f32_16x16x32_f16(ha[c], wh[1][c], az, 0, 0, 0);
                aghn = __builtin_amdgcn_mfma_f32_16x16x32_f16(ha[c], wh[2][c], aghn, 0, 0, 0);
                agin = __builtin_amdgcn_mfma_f32_16x16x32_f16(ha[c], wxn[c],  agin, 0, 0, 0);
            }

            const float r = fast_sigmoid(ar[0]);
            const float z = fast_sigmoid(az[0]);
            const float n = fast_tanh(agin[0] + r * aghn[0]);
            const float h = n + z * (hold[ch] - n);
            hold[ch] = h;
            hwr[quad * HS + j] = (_Float16)h;
        }
        LDS_BARRIER();
    }

    // tail projection: o_{T-1} = d_128 @ linW^T + lb (d_128 in hb[ch][0])
    if (wv < 3) {
        #pragma unroll
        for (int ch = 0; ch < NCH; ++ch) {
            const _Float16* hrd = hb[ch][0];
            half8 ha[4];
            #pragma unroll
            for (int c = 0; c < 4; ++c)
                ha[c] = *(const half8*)&hrd[arow * HS + c * 32 + quad * 8];
            f32x4 al = { lb, lb, lb, lb };
            #pragma unroll
            for (int c = 0; c < 4; ++c)
                al = __builtin_amdgcn_mfma_f32_16x16x32_f16(ha[c], wl[c], al, 0, 0, 0);
            if (nv)
                out[((size_t)(b0 + RC * ch + quad) * T_SEQ + (T_SEQ - 1)) * X_DIM + nlin] = al[0];
        }
    }
}

extern "C" void kernel_launch(void* const* d_in, const int* in_sizes, int n_in,
                              void* d_out, int out_size, void* d_ws, size_t ws_size,
                              hipStream_t stream) {
    (void)in_sizes; (void)n_in; (void)d_ws; (void)ws_size; (void)out_size;
    const float* x    = (const float*)d_in[0];
    const float* eWih = (const float*)d_in[1];
    const float* eWhh = (const float*)d_in[2];
    const float* ebih = (const float*)d_in[3];
    const float* ebhh = (const float*)d_in[4];
    const float* dWih = (const float*)d_in[5];
    const float* dWhh = (const float*)d_in[6];
    const float* dbih = (const float*)d_in[7];
    const float* dbhh = (const float*)d_in[8];
    const float* linW = (const float*)d_in[9];
    const float* linb = (const float*)d_in[10];
    float* out = (float*)d_out;

    rae_gru_kernel<<<dim3(B_TOT / BT), dim3(512), 0, stream>>>(
        x, eWih, eWhh, ebih, ebhh, dWih, dWhh, dbih, dbhh, linW, linb, out);
}